// Round 2
// baseline (611.930 us; speedup 1.0000x reference)
//
#include <hip/hip_runtime.h>
#include <math.h>

#define TAU_INV 14.285714285714286f

// ws layout (float offsets)
#define WS_HS    0                         // [32*16] sum of qs over pixels
#define WS_HT    512                       // [32*16] sum of qt over pixels
#define WS_MU    1024                      // [16*128] sum qt*zt
#define WS_PCS   3072                      // [16*256] C @ Ws
#define WS_PCT   7168                      // [16*512] C @ Wt
#define WS_TL    15360                     // [32*1024*128] low-res teacher features
#define WS_TLC   (15360 + 32*1024*128)     // [32*1024*16]  low-res teacher logits (t.C^T)

// ---------------------------------------------------------------- prep: PCs = C@Ws, PCt = C@Wt
__global__ __launch_bounds__(256) void prep_kernel(
    const float* __restrict__ C, const float* __restrict__ Ws,
    const float* __restrict__ Wt, float* __restrict__ PCs, float* __restrict__ PCt)
{
    int g = blockIdx.x * 256 + threadIdx.x;   // grid 48*256 = 12288 = 4096 + 8192
    if (g < 4096) {
        int m = g >> 8, c = g & 255;
        float s = 0.f;
        #pragma unroll 8
        for (int dd = 0; dd < 128; dd++) s = fmaf(C[m*128+dd], Ws[dd*256 + c], s);
        PCs[g] = s;
    } else {
        int g2 = g - 4096;
        int m = g2 >> 9, c = g2 & 511;
        float s = 0.f;
        #pragma unroll 8
        for (int dd = 0; dd < 128; dd++) s = fmaf(C[m*128+dd], Wt[dd*512 + c], s);
        PCt[g2] = s;
    }
}

// ---------------------------------------------------------------- student: GEMM tile + fused softmax -> hs
// grid 2048 = 32 b * 64 tiles of 64 pixels; block 256
__global__ __launch_bounds__(256) void student_kernel(
    const float* __restrict__ fs4, const float* __restrict__ Ws,
    const float* __restrict__ PCs, float* __restrict__ hs_acc)
{
    __shared__ float As[32][64];       // [c][n]
    __shared__ float Wl[32][136];      // [c][d], pad 8
    __shared__ float Pl[32][16];       // [c][m]
    __shared__ float out2_s[64][17];   // [n][m] raw logits (s . C_m)
    __shared__ float nrm2_s[64];
    const int HW = 4096, CS = 256;
    int tid = threadIdx.x;
    int b  = blockIdx.x >> 6;
    int n0 = (blockIdx.x & 63) * 64;
    int tx = tid & 15, ty = tid >> 4;      // micro-tile: 4 pixels (tx) x 8 dims (ty)
    const float* Ab = fs4 + (size_t)b * CS * HW + n0;

    float acc[4][8];
    float p2[4] = {0.f, 0.f, 0.f, 0.f};
    #pragma unroll
    for (int i = 0; i < 4; i++)
        #pragma unroll
        for (int j = 0; j < 8; j++) acc[i][j] = 0.f;
    if (tid < 64) nrm2_s[tid] = 0.f;

    for (int k = 0; k < CS; k += 32) {
        #pragma unroll
        for (int r = 0; r < 2; r++) {                     // As: 512 float4
            int f4 = r*256 + tid;
            int c = f4 >> 4, nn = (f4 & 15) * 4;
            *(float4*)&As[c][nn] = *(const float4*)&Ab[(size_t)(k + c) * HW + nn];
        }
        #pragma unroll
        for (int r = 0; r < 16; r++) {                    // Wl: 4096 scalars (L2-resident)
            int idx = r*256 + tid;
            int c = idx & 31, dd = idx >> 5;
            Wl[c][dd] = Ws[dd*CS + k + c];
        }
        {
            int idx = tid*2;
            int m0 = idx & 15, c0 = idx >> 4;
            Pl[c0][m0] = PCs[m0*CS + k + c0];
            int m1 = (idx+1) & 15, c1 = (idx+1) >> 4;
            Pl[c1][m1] = PCs[m1*CS + k + c1];
        }
        __syncthreads();
        #pragma unroll
        for (int kk = 0; kk < 32; kk++) {
            float4 av = *(const float4*)&As[kk][tx*4];
            float4 w0 = *(const float4*)&Wl[kk][ty*8];
            float4 w1 = *(const float4*)&Wl[kk][ty*8+4];
            float pw = Pl[kk][ty];
            float a[4] = {av.x, av.y, av.z, av.w};
            float w[8] = {w0.x,w0.y,w0.z,w0.w,w1.x,w1.y,w1.z,w1.w};
            #pragma unroll
            for (int i = 0; i < 4; i++) {
                #pragma unroll
                for (int j = 0; j < 8; j++) acc[i][j] = fmaf(a[i], w[j], acc[i][j]);
                p2[i] = fmaf(a[i], pw, p2[i]);
            }
        }
        __syncthreads();
    }
    // |s|^2 partials + logits to LDS
    #pragma unroll
    for (int i = 0; i < 4; i++) {
        out2_s[tx*4+i][ty] = p2[i];
        float s = 0.f;
        #pragma unroll
        for (int j = 0; j < 8; j++) s = fmaf(acc[i][j], acc[i][j], s);
        atomicAdd(&nrm2_s[tx*4+i], s);
    }
    __syncthreads();
    if (tid < 64) {                                       // one wave: per-pixel softmax + reduce
        float inv = 1.f / fmaxf(sqrtf(nrm2_s[tid]), 1e-12f);
        float e[16];
        float mx = -1e30f;
        #pragma unroll
        for (int m = 0; m < 16; m++) {
            e[m] = out2_s[tid][m] * inv * TAU_INV;
            mx = fmaxf(mx, e[m]);
        }
        float sum = 0.f;
        #pragma unroll
        for (int m = 0; m < 16; m++) { e[m] = expf(e[m] - mx); sum += e[m]; }
        float isum = 1.f / sum;
        #pragma unroll
        for (int m = 0; m < 16; m++) {
            float v = e[m] * isum;
            v += __shfl_xor(v, 1);  v += __shfl_xor(v, 2);  v += __shfl_xor(v, 4);
            v += __shfl_xor(v, 8);  v += __shfl_xor(v, 16); v += __shfl_xor(v, 32);
            if (tid == 0) atomicAdd(&hs_acc[b*16 + m], v);
        }
    }
}

// ---------------------------------------------------------------- teacher low-res GEMM: tl, tlC
// grid 512 = 32 b * 16 tiles; block 256
__global__ __launch_bounds__(256) void teacher_lowres_kernel(
    const float* __restrict__ ft, const float* __restrict__ Wt,
    const float* __restrict__ PCt, float* __restrict__ tl, float* __restrict__ tlC)
{
    __shared__ float As[32][64];
    __shared__ float Wl[32][136];
    __shared__ float Pl[32][16];
    const int HW = 1024, CT = 512;
    int tid = threadIdx.x;
    int b  = blockIdx.x >> 4;
    int n0 = (blockIdx.x & 15) * 64;
    int tx = tid & 15, ty = tid >> 4;
    const float* Ab = ft + (size_t)b * CT * HW + n0;

    float acc[4][8];
    float p2[4] = {0.f, 0.f, 0.f, 0.f};
    #pragma unroll
    for (int i = 0; i < 4; i++)
        #pragma unroll
        for (int j = 0; j < 8; j++) acc[i][j] = 0.f;

    for (int k = 0; k < CT; k += 32) {
        #pragma unroll
        for (int r = 0; r < 2; r++) {
            int f4 = r*256 + tid;
            int c = f4 >> 4, nn = (f4 & 15) * 4;
            *(float4*)&As[c][nn] = *(const float4*)&Ab[(size_t)(k + c) * HW + nn];
        }
        #pragma unroll
        for (int r = 0; r < 16; r++) {
            int idx = r*256 + tid;
            int c = idx & 31, dd = idx >> 5;
            Wl[c][dd] = Wt[dd*CT + k + c];
        }
        {
            int idx = tid*2;
            int m0 = idx & 15, c0 = idx >> 4;
            Pl[c0][m0] = PCt[m0*CT + k + c0];
            int m1 = (idx+1) & 15, c1 = (idx+1) >> 4;
            Pl[c1][m1] = PCt[m1*CT + k + c1];
        }
        __syncthreads();
        #pragma unroll
        for (int kk = 0; kk < 32; kk++) {
            float4 av = *(const float4*)&As[kk][tx*4];
            float4 w0 = *(const float4*)&Wl[kk][ty*8];
            float4 w1 = *(const float4*)&Wl[kk][ty*8+4];
            float pw = Pl[kk][ty];
            float a[4] = {av.x, av.y, av.z, av.w};
            float w[8] = {w0.x,w0.y,w0.z,w0.w,w1.x,w1.y,w1.z,w1.w};
            #pragma unroll
            for (int i = 0; i < 4; i++) {
                #pragma unroll
                for (int j = 0; j < 8; j++) acc[i][j] = fmaf(a[i], w[j], acc[i][j]);
                p2[i] = fmaf(a[i], pw, p2[i]);
            }
        }
        __syncthreads();
    }
    #pragma unroll
    for (int i = 0; i < 4; i++) {
        int n = n0 + tx*4 + i;
        float* dst = tl + ((size_t)(b*1024 + n))*128 + ty*8;
        float4 o0 = {acc[i][0],acc[i][1],acc[i][2],acc[i][3]};
        float4 o1 = {acc[i][4],acc[i][5],acc[i][6],acc[i][7]};
        *(float4*)dst = o0;
        *(float4*)(dst+4) = o1;
        tlC[(size_t)(b*1024 + n)*16 + ty] = p2[i];
    }
}

// ---------------------------------------------------------------- teacher high-res: upsample + softmax + ht/mu
// grid 512 = 32 b * 16 row-groups (4 rows each); block 256 (4 threads per pixel)
__global__ __launch_bounds__(256) void teacher_highres_kernel(
    const float* __restrict__ tl, const float* __restrict__ tlC,
    float* __restrict__ ht_acc, float* __restrict__ mu_acc)
{
    __shared__ float t_s[64][132];
    __shared__ float qs_s[64][16];   // qt * inv_norm
    __shared__ float ht_part[16];
    int tid = threadIdx.x;
    int b = blockIdx.x >> 4, y0 = (blockIdx.x & 15) * 4;
    if (tid < 16) ht_part[tid] = 0.f;

    int p = tid >> 2, q = tid & 3;           // pixel x=p, dims q*32..q*32+31
    int jx = p >> 1;
    int c0, c1; float wx0, wx1;
    if ((p & 1) == 0) { c0 = jx - 1; c1 = jx;     wx0 = 0.25f; wx1 = 0.75f; }
    else              { c0 = jx;     c1 = jx + 1; wx0 = 0.75f; wx1 = 0.25f; }
    c0 = max(c0, 0); c1 = min(c1, 31);

    int mm = tid >> 4, d8 = (tid & 15) * 8;  // mini-GEMM role
    float a8[8] = {0.f,0.f,0.f,0.f,0.f,0.f,0.f,0.f};
    size_t base = (size_t)b * 1024;

    for (int ry = 0; ry < 4; ry++) {
        int y = y0 + ry;
        int jy = y >> 1;
        int r0, r1; float wy0, wy1;
        if ((y & 1) == 0) { r0 = jy - 1; r1 = jy;     wy0 = 0.25f; wy1 = 0.75f; }
        else              { r0 = jy;     r1 = jy + 1; wy0 = 0.75f; wy1 = 0.25f; }
        r0 = max(r0, 0); r1 = min(r1, 31);

        const float* v00 = tl + (base + r0*32 + c0)*128 + q*32;
        const float* v01 = tl + (base + r0*32 + c1)*128 + q*32;
        const float* v10 = tl + (base + r1*32 + c0)*128 + q*32;
        const float* v11 = tl + (base + r1*32 + c1)*128 + q*32;

        float tc[32];
        float nr = 0.f;
        #pragma unroll
        for (int i = 0; i < 32; i += 4) {
            float4 a  = *(const float4*)(v00+i);
            float4 bb = *(const float4*)(v01+i);
            float4 cc = *(const float4*)(v10+i);
            float4 dd = *(const float4*)(v11+i);
            float t0 = wy0*fmaf(wx0,a.x,wx1*bb.x) + wy1*fmaf(wx0,cc.x,wx1*dd.x);
            float t1 = wy0*fmaf(wx0,a.y,wx1*bb.y) + wy1*fmaf(wx0,cc.y,wx1*dd.y);
            float t2 = wy0*fmaf(wx0,a.z,wx1*bb.z) + wy1*fmaf(wx0,cc.z,wx1*dd.z);
            float t3 = wy0*fmaf(wx0,a.w,wx1*bb.w) + wy1*fmaf(wx0,cc.w,wx1*dd.w);
            tc[i]=t0; tc[i+1]=t1; tc[i+2]=t2; tc[i+3]=t3;
            nr += t0*t0 + t1*t1 + t2*t2 + t3*t3;
        }
        nr += __shfl_xor(nr, 1);
        nr += __shfl_xor(nr, 2);
        float inv = 1.f / fmaxf(sqrtf(nr), 1e-12f);
        #pragma unroll
        for (int i = 0; i < 32; i += 4) {
            float4 o = {tc[i], tc[i+1], tc[i+2], tc[i+3]};
            *(float4*)&t_s[p][q*32+i] = o;
        }
        __syncthreads();   // t_s ready (also ht_part zero on first iter)

        if (q == 0) {
            const float* g00 = tlC + (base + r0*32 + c0)*16;
            const float* g01 = tlC + (base + r0*32 + c1)*16;
            const float* g10 = tlC + (base + r1*32 + c0)*16;
            const float* g11 = tlC + (base + r1*32 + c1)*16;
            float e[16]; float mx = -1e30f;
            #pragma unroll
            for (int m = 0; m < 16; m++) {
                float l = wy0*fmaf(wx0,g00[m],wx1*g01[m]) + wy1*fmaf(wx0,g10[m],wx1*g11[m]);
                e[m] = l * inv * TAU_INV;
                mx = fmaxf(mx, e[m]);
            }
            float sum = 0.f;
            #pragma unroll
            for (int m = 0; m < 16; m++) { e[m] = expf(e[m] - mx); sum += e[m]; }
            float isum = 1.f / sum;
            #pragma unroll
            for (int m = 0; m < 16; m++) {
                float qt = e[m] * isum;
                qs_s[p][m] = qt * inv;
                atomicAdd(&ht_part[m], qt);
            }
        }
        __syncthreads();   // qs_s ready

        // mini-GEMM: a8[m][d8..] += sum_p qs_s[p][m] * t_s[p][dim]
        for (int pp = 0; pp < 64; pp++) {
            float qv = qs_s[pp][mm];
            float4 t0 = *(const float4*)&t_s[pp][d8];
            float4 t1 = *(const float4*)&t_s[pp][d8+4];
            a8[0] = fmaf(qv, t0.x, a8[0]); a8[1] = fmaf(qv, t0.y, a8[1]);
            a8[2] = fmaf(qv, t0.z, a8[2]); a8[3] = fmaf(qv, t0.w, a8[3]);
            a8[4] = fmaf(qv, t1.x, a8[4]); a8[5] = fmaf(qv, t1.y, a8[5]);
            a8[6] = fmaf(qv, t1.z, a8[6]); a8[7] = fmaf(qv, t1.w, a8[7]);
        }
        __syncthreads();   // done reading before next row overwrites
    }
    #pragma unroll
    for (int j = 0; j < 8; j++) atomicAdd(&mu_acc[mm*128 + d8 + j], a8[j]);
    if (tid < 16) atomicAdd(&ht_acc[b*16 + tid], ht_part[tid]);
}

// ---------------------------------------------------------------- finalize: denom, mu, C_new, kl
__global__ __launch_bounds__(256) void finalize_kernel(
    const float* __restrict__ C, const float* __restrict__ hs_acc,
    const float* __restrict__ ht_acc, const float* __restrict__ mu_acc,
    float* __restrict__ out)
{
    __shared__ float denom_s[16];
    __shared__ float red[256];
    int tid = threadIdx.x;
    if (tid < 16) {
        float s = 0.f;
        #pragma unroll
        for (int bb = 0; bb < 32; bb++) s += ht_acc[bb*16 + tid];
        denom_s[tid] = s + 1e-6f;
    }
    __syncthreads();
    int m = tid >> 4, dbase = (tid & 15) * 8;   // 16 threads per codebook row
    float v[8]; float ss = 0.f;
    #pragma unroll
    for (int j = 0; j < 8; j++) {
        v[j] = mu_acc[m*128 + dbase + j] / denom_s[m];
        ss = fmaf(v[j], v[j], ss);
    }
    ss += __shfl_xor(ss, 1); ss += __shfl_xor(ss, 2);
    ss += __shfl_xor(ss, 4); ss += __shfl_xor(ss, 8);
    float invn = 1.f / fmaxf(sqrtf(ss), 1e-12f);
    float cn[8]; float cs = 0.f;
    #pragma unroll
    for (int j = 0; j < 8; j++) {
        cn[j] = 0.99f * C[m*128 + dbase + j] + 0.01f * (v[j] * invn);
        cs = fmaf(cn[j], cn[j], cs);
    }
    cs += __shfl_xor(cs, 1); cs += __shfl_xor(cs, 2);
    cs += __shfl_xor(cs, 4); cs += __shfl_xor(cs, 8);
    float invc = 1.f / fmaxf(sqrtf(cs), 1e-12f);
    #pragma unroll
    for (int j = 0; j < 8; j++) out[1 + m*128 + dbase + j] = cn[j] * invc;

    float kacc = 0.f;
    for (int idx = tid; idx < 512; idx += 256) {
        float htv = ht_acc[idx] * (1.f/4096.f);
        float hsv = hs_acc[idx] * (1.f/4096.f);
        float t1 = (htv > 0.f) ? htv * logf(htv) : 0.f;
        kacc += t1 - htv * logf(hsv + 1e-12f);
    }
    red[tid] = kacc;
    __syncthreads();
    for (int s2 = 128; s2 > 0; s2 >>= 1) {
        if (tid < s2) red[tid] += red[tid + s2];
        __syncthreads();
    }
    if (tid == 0) out[0] = red[0] * (1.f/32.f);
}

extern "C" void kernel_launch(void* const* d_in, const int* in_sizes, int n_in,
                              void* d_out, int out_size, void* d_ws, size_t ws_size,
                              hipStream_t stream) {
    const float* fs4 = (const float*)d_in[0];
    const float* ft  = (const float*)d_in[1];
    const float* Ws  = (const float*)d_in[2];
    const float* Wt  = (const float*)d_in[3];
    const float* C   = (const float*)d_in[4];
    float* out = (float*)d_out;
    float* ws  = (float*)d_ws;
    float* hs_acc = ws + WS_HS;
    float* ht_acc = ws + WS_HT;
    float* mu_acc = ws + WS_MU;
    float* PCs = ws + WS_PCS;
    float* PCt = ws + WS_PCT;
    float* tl  = ws + WS_TL;
    float* tlC = ws + WS_TLC;

    hipMemsetAsync(ws, 0, 3072 * sizeof(float), stream);
    hipLaunchKernelGGL(prep_kernel, dim3(48), dim3(256), 0, stream, C, Ws, Wt, PCs, PCt);
    hipLaunchKernelGGL(student_kernel, dim3(2048), dim3(256), 0, stream, fs4, Ws, PCs, hs_acc);
    hipLaunchKernelGGL(teacher_lowres_kernel, dim3(512), dim3(256), 0, stream, ft, Wt, PCt, tl, tlC);
    hipLaunchKernelGGL(teacher_highres_kernel, dim3(512), dim3(256), 0, stream, tl, tlC, ht_acc, mu_acc);
    hipLaunchKernelGGL(finalize_kernel, dim3(1), dim3(256), 0, stream, C, hs_acc, ht_acc, mu_acc, out);
}

// Round 3
// 462.500 us; speedup vs baseline: 1.3231x; 1.3231x over previous
//
#include <hip/hip_runtime.h>
#include <math.h>

#define TAU_INV 14.285714285714286f

using short8 = __attribute__((ext_vector_type(8))) short;
using f32x4  = __attribute__((ext_vector_type(4))) float;

// ws layout (float offsets)
#define WS_HS   0
#define WS_HT   512
#define WS_MU   1024
#define WS_TL   4096
#define WS_TLC  (4096 + 32*1024*128)
#define WS_WSH  (WS_TLC + 32*1024*16)      // ushort[160*256]
#define WS_WSL  (WS_WSH + 20480)
#define WS_WTH  (WS_WSL + 20480)           // ushort[160*512]
#define WS_WTL  (WS_WTH + 40960)

__device__ __forceinline__ uint bf16rne(float f) {
    uint u = __float_as_uint(f);
    return (u + 0x7fffu + ((u >> 16) & 1u)) >> 16;
}

// ---------------------------------------------------------------- prep: pack W(+PC rows) into bf16 hi/lo planes
// rows 0-127: W; rows 128-143: C@W (logit rows); rows 144-159: zero. grid 480*256 covers 160*(256+512)
__global__ __launch_bounds__(256) void prep_kernel(
    const float* __restrict__ C, const float* __restrict__ Ws, const float* __restrict__ Wt,
    ushort* __restrict__ Wsh, ushort* __restrict__ Wsl,
    ushort* __restrict__ Wth, ushort* __restrict__ Wtl)
{
    int id = blockIdx.x * 256 + threadIdx.x;
    float v; ushort* H; ushort* L; int idx;
    if (id < 160*256) {
        int row = id >> 8, c = id & 255;
        if (row < 128) v = Ws[row*256 + c];
        else if (row < 144) {
            v = 0.f; int m = row - 128;
            #pragma unroll 8
            for (int dd = 0; dd < 128; dd++) v = fmaf(C[m*128+dd], Ws[dd*256 + c], v);
        } else v = 0.f;
        H = Wsh; L = Wsl; idx = id;
    } else {
        int id2 = id - 160*256;
        int row = id2 >> 9, c = id2 & 511;
        if (row < 128) v = Wt[row*512 + c];
        else if (row < 144) {
            v = 0.f; int m = row - 128;
            #pragma unroll 8
            for (int dd = 0; dd < 128; dd++) v = fmaf(C[m*128+dd], Wt[dd*512 + c], v);
        } else v = 0.f;
        H = Wth; L = Wtl; idx = id2;
    }
    uint h = bf16rne(v);
    float hf = __uint_as_float(h << 16);
    uint l = bf16rne(v - hf);
    H[idx] = (ushort)h; L[idx] = (ushort)l;
}

// ---------------------------------------------------------------- split-bf16 MFMA GEMM
// D[144 x 128px] per block: rows 0-127 = features, 128-143 = codebook logits.
// 4 waves: wd in {0,1} -> d-tiles {0..4} / {5..8} (80/64 rows), wn in {0,1} -> 64 px each.
// LDS: A planar hi/lo bf16 [144][32] (16B-granule swizzle slot^=row&3),
//      B u32-packed (hi<<16|lo) [128px][32c] (granule swizzle slot^= (row>>2)&7).
template<bool STUDENT, int CIN, int HW>
__global__ __launch_bounds__(256, 2) void gemm_kernel(
    const float* __restrict__ X, const ushort* __restrict__ Wh, const ushort* __restrict__ Wl,
    float* __restrict__ hs_acc, float* __restrict__ tl, float* __restrict__ tlC)
{
    __shared__ __align__(16) ushort Ah[144*32];
    __shared__ __align__(16) ushort Al[144*32];
    __shared__ __align__(16) uint   Bpk[128*32];
    __shared__ float nrm2_lds[128];

    const int tid  = threadIdx.x;
    const int lane = tid & 63;
    const int w    = tid >> 6, wd = w >> 1, wn = w & 1;
    const int g    = lane >> 4, m16 = lane & 15;
    const int ST   = (wd == 0) ? 5 : 4;           // d-tiles this wave owns
    const int tiles_b = HW / 128;
    const int b   = blockIdx.x / tiles_b;
    const int n0  = (blockIdx.x % tiles_b) * 128;
    const float* Xb = X + (size_t)b * CIN * HW + n0;

    f32x4 acc[5][4];
    #pragma unroll
    for (int i = 0; i < 5; i++)
        #pragma unroll
        for (int j = 0; j < 4; j++) acc[i][j] = (f32x4){0.f, 0.f, 0.f, 0.f};

    const int cb = (tid & 7) * 4;     // B staging: c base
    const int nf = tid >> 3;          // B staging: n-float4 index 0..31

    for (int k0 = 0; k0 < CIN; k0 += 32) {
        // ---- stage A: 576 16B-granules per plane (144 rows x 4 slots)
        #pragma unroll
        for (int r = 0; r < 3; r++) {
            int id = tid + r * 256;
            if (r < 2 || id < 576) {
                int row = id >> 2, slot = id & 3;
                int dst = row * 32 + ((slot ^ (row & 3)) << 3);
                int src = row * CIN + k0 + slot * 8;
                *(uint4*)&Ah[dst] = *(const uint4*)&Wh[src];
                *(uint4*)&Al[dst] = *(const uint4*)&Wl[src];
            }
        }
        // ---- stage B: 4 float4 loads (c=cb..cb+3, n=4nf..4nf+3), split+pack, transposed write
        float4 vv[4];
        #pragma unroll
        for (int i = 0; i < 4; i++)
            vv[i] = *(const float4*)&Xb[(size_t)(k0 + cb + i) * HW + nf * 4];
        #pragma unroll
        for (int j = 0; j < 4; j++) {
            uint q[4];
            #pragma unroll
            for (int i = 0; i < 4; i++) {
                float f = (j == 0) ? vv[i].x : (j == 1) ? vv[i].y : (j == 2) ? vv[i].z : vv[i].w;
                uint h = bf16rne(f);
                float hf = __uint_as_float(h << 16);
                uint lo = bf16rne(f - hf);
                q[i] = (h << 16) | lo;
            }
            int row = nf * 4 + j;
            int dst = row * 32 + (((tid & 7) ^ (nf & 7)) << 2);
            *(uint4*)&Bpk[dst] = make_uint4(q[0], q[1], q[2], q[3]);
        }
        __syncthreads();

        // ---- fragments + MFMA
        short8 ah[5], al[5];
        #pragma unroll
        for (int ti = 0; ti < 5; ti++) {
            if (ti < ST) {
                int row = wd * 80 + ti * 16 + m16;
                int ad = row * 32 + ((g ^ (row & 3)) << 3);
                ah[ti] = *(const short8*)&Ah[ad];
                al[ti] = *(const short8*)&Al[ad];
            }
        }
        #pragma unroll
        for (int nj = 0; nj < 4; nj++) {
            int row = wn * 64 + nj * 16 + m16;
            int key = (row >> 2) & 7;
            const uint4 q0 = *(const uint4*)&Bpk[row * 32 + (((2*g)   ^ key) << 2)];
            const uint4 q1 = *(const uint4*)&Bpk[row * 32 + (((2*g+1) ^ key) << 2)];
            uint4 bhv, blv;
            bhv.x = __builtin_amdgcn_perm(q0.y, q0.x, 0x07060302u);
            bhv.y = __builtin_amdgcn_perm(q0.w, q0.z, 0x07060302u);
            bhv.z = __builtin_amdgcn_perm(q1.y, q1.x, 0x07060302u);
            bhv.w = __builtin_amdgcn_perm(q1.w, q1.z, 0x07060302u);
            blv.x = __builtin_amdgcn_perm(q0.y, q0.x, 0x05040100u);
            blv.y = __builtin_amdgcn_perm(q0.w, q0.z, 0x05040100u);
            blv.z = __builtin_amdgcn_perm(q1.y, q1.x, 0x05040100u);
            blv.w = __builtin_amdgcn_perm(q1.w, q1.z, 0x05040100u);
            short8 bh = *(short8*)&bhv;
            short8 bl = *(short8*)&blv;
            #pragma unroll
            for (int ti = 0; ti < 5; ti++) {
                if (ti < ST) {
                    acc[ti][nj] = __builtin_amdgcn_mfma_f32_16x16x32_bf16(ah[ti], bh, acc[ti][nj], 0, 0, 0);
                    acc[ti][nj] = __builtin_amdgcn_mfma_f32_16x16x32_bf16(al[ti], bh, acc[ti][nj], 0, 0, 0);
                    acc[ti][nj] = __builtin_amdgcn_mfma_f32_16x16x32_bf16(ah[ti], bl, acc[ti][nj], 0, 0, 0);
                }
            }
        }
        __syncthreads();
    }

    if constexpr (STUDENT) {
        // |s|^2 partials: wd0 -> tiles 0-4 (d 0-79), wd1 -> tiles 0-2 (d 80-127); tile 3 of wd1 = logits
        float nrm_own[4];
        #pragma unroll
        for (int nj = 0; nj < 4; nj++) {
            float v = 0.f;
            int st = (wd == 0) ? 5 : 3;
            #pragma unroll
            for (int ti = 0; ti < 5; ti++) {
                if (ti < st) {
                    f32x4 a = acc[ti][nj];
                    v = fmaf(a.x, a.x, v); v = fmaf(a.y, a.y, v);
                    v = fmaf(a.z, a.z, v); v = fmaf(a.w, a.w, v);
                }
            }
            v += __shfl_xor(v, 16); v += __shfl_xor(v, 32);
            nrm_own[nj] = v;
        }
        if (wd == 0 && g == 0) {
            #pragma unroll
            for (int nj = 0; nj < 4; nj++)
                nrm2_lds[wn * 64 + nj * 16 + m16] = nrm_own[nj];
        }
        __syncthreads();
        if (wd == 1) {
            float hsl[4] = {0.f, 0.f, 0.f, 0.f};
            #pragma unroll
            for (int nj = 0; nj < 4; nj++) {
                int nloc = wn * 64 + nj * 16 + m16;
                float nrm2 = nrm2_lds[nloc] + nrm_own[nj];
                float sc = TAU_INV / fmaxf(sqrtf(nrm2), 1e-12f);
                float e0 = acc[3][nj].x * sc, e1 = acc[3][nj].y * sc;
                float e2 = acc[3][nj].z * sc, e3 = acc[3][nj].w * sc;
                float mx = fmaxf(fmaxf(e0, e1), fmaxf(e2, e3));
                mx = fmaxf(mx, __shfl_xor(mx, 16)); mx = fmaxf(mx, __shfl_xor(mx, 32));
                e0 = expf(e0 - mx); e1 = expf(e1 - mx); e2 = expf(e2 - mx); e3 = expf(e3 - mx);
                float s = e0 + e1 + e2 + e3;
                s += __shfl_xor(s, 16); s += __shfl_xor(s, 32);
                float is = 1.f / s;
                hsl[0] = fmaf(e0, is, hsl[0]); hsl[1] = fmaf(e1, is, hsl[1]);
                hsl[2] = fmaf(e2, is, hsl[2]); hsl[3] = fmaf(e3, is, hsl[3]);
            }
            #pragma unroll
            for (int r = 0; r < 4; r++) {
                float v = hsl[r];
                v += __shfl_xor(v, 1); v += __shfl_xor(v, 2);
                v += __shfl_xor(v, 4); v += __shfl_xor(v, 8);
                if (m16 == 0) atomicAdd(&hs_acc[b * 16 + 4 * g + r], v);
            }
        }
    } else {
        // teacher: write tl (features) + tlC (logits)
        #pragma unroll
        for (int ti = 0; ti < 5; ti++) {
            if (ti < ST) {
                int d0 = wd * 80 + ti * 16;
                #pragma unroll
                for (int nj = 0; nj < 4; nj++) {
                    int n = n0 + wn * 64 + nj * 16 + m16;
                    if (d0 < 128)
                        *(f32x4*)&tl[((size_t)(b * 1024 + n)) * 128 + d0 + 4 * g] = acc[ti][nj];
                    else
                        *(f32x4*)&tlC[((size_t)(b * 1024 + n)) * 16 + 4 * g] = acc[ti][nj];
                }
            }
        }
    }
}

// ---------------------------------------------------------------- teacher high-res: upsample + softmax + ht/mu
// grid 512 = 32 b * 16 row-groups (4 rows each); block 256 (4 threads per pixel)
__global__ __launch_bounds__(256) void teacher_highres_kernel(
    const float* __restrict__ tl, const float* __restrict__ tlC,
    float* __restrict__ ht_acc, float* __restrict__ mu_acc)
{
    __shared__ float t_s[64][132];
    __shared__ float qs_s[64][16];   // raw qt
    __shared__ float inv_s[64];      // 1/|t_up|
    int tid = threadIdx.x;
    int b = blockIdx.x >> 4, y0 = (blockIdx.x & 15) * 4;

    int p = tid >> 2, q = tid & 3;           // pixel x=p, dims q*32..q*32+31
    int jx = p >> 1;
    int c0, c1; float wx0, wx1;
    if ((p & 1) == 0) { c0 = jx - 1; c1 = jx;     wx0 = 0.25f; wx1 = 0.75f; }
    else              { c0 = jx;     c1 = jx + 1; wx0 = 0.75f; wx1 = 0.25f; }
    c0 = max(c0, 0); c1 = min(c1, 31);

    int mm = tid >> 4, d8 = (tid & 15) * 8;  // mini-GEMM role
    float a8[8] = {0.f,0.f,0.f,0.f,0.f,0.f,0.f,0.f};
    float htl = 0.f;
    size_t base = (size_t)b * 1024;

    for (int ry = 0; ry < 4; ry++) {
        int y = y0 + ry;
        int jy = y >> 1;
        int r0, r1; float wy0, wy1;
        if ((y & 1) == 0) { r0 = jy - 1; r1 = jy;     wy0 = 0.25f; wy1 = 0.75f; }
        else              { r0 = jy;     r1 = jy + 1; wy0 = 0.75f; wy1 = 0.25f; }
        r0 = max(r0, 0); r1 = min(r1, 31);

        const float* v00 = tl + (base + r0*32 + c0)*128 + q*32;
        const float* v01 = tl + (base + r0*32 + c1)*128 + q*32;
        const float* v10 = tl + (base + r1*32 + c0)*128 + q*32;
        const float* v11 = tl + (base + r1*32 + c1)*128 + q*32;

        float tc[32];
        float nr = 0.f;
        #pragma unroll
        for (int i = 0; i < 32; i += 4) {
            float4 a  = *(const float4*)(v00+i);
            float4 bb = *(const float4*)(v01+i);
            float4 cc = *(const float4*)(v10+i);
            float4 dd = *(const float4*)(v11+i);
            float t0 = wy0*fmaf(wx0,a.x,wx1*bb.x) + wy1*fmaf(wx0,cc.x,wx1*dd.x);
            float t1 = wy0*fmaf(wx0,a.y,wx1*bb.y) + wy1*fmaf(wx0,cc.y,wx1*dd.y);
            float t2 = wy0*fmaf(wx0,a.z,wx1*bb.z) + wy1*fmaf(wx0,cc.z,wx1*dd.z);
            float t3 = wy0*fmaf(wx0,a.w,wx1*bb.w) + wy1*fmaf(wx0,cc.w,wx1*dd.w);
            tc[i]=t0; tc[i+1]=t1; tc[i+2]=t2; tc[i+3]=t3;
            nr += t0*t0 + t1*t1 + t2*t2 + t3*t3;
        }
        nr += __shfl_xor(nr, 1);
        nr += __shfl_xor(nr, 2);
        float inv = 1.f / fmaxf(sqrtf(nr), 1e-12f);
        #pragma unroll
        for (int i = 0; i < 32; i += 4) {
            float4 o = {tc[i], tc[i+1], tc[i+2], tc[i+3]};
            *(float4*)&t_s[p][q*32+i] = o;
        }
        if (q == 0) inv_s[p] = inv;
        __syncthreads();

        if (q == 0) {
            const float* g00 = tlC + (base + r0*32 + c0)*16;
            const float* g01 = tlC + (base + r0*32 + c1)*16;
            const float* g10 = tlC + (base + r1*32 + c0)*16;
            const float* g11 = tlC + (base + r1*32 + c1)*16;
            float e[16]; float mx = -1e30f;
            #pragma unroll
            for (int m = 0; m < 16; m++) {
                float l = wy0*fmaf(wx0,g00[m],wx1*g01[m]) + wy1*fmaf(wx0,g10[m],wx1*g11[m]);
                e[m] = l * inv * TAU_INV;
                mx = fmaxf(mx, e[m]);
            }
            float sum = 0.f;
            #pragma unroll
            for (int m = 0; m < 16; m++) { e[m] = expf(e[m] - mx); sum += e[m]; }
            float isum = 1.f / sum;
            #pragma unroll
            for (int m = 0; m < 16; m++) qs_s[p][m] = e[m] * isum;
        }
        __syncthreads();

        // mini-GEMM: a8 += sum_p (qt * inv) * t_s ; ht: thread (tid&15)==0 sums qt for m=mm
        for (int pp = 0; pp < 64; pp++) {
            float qraw = qs_s[pp][mm];
            if ((tid & 15) == 0) htl += qraw;
            float qv = qraw * inv_s[pp];
            float4 t0 = *(const float4*)&t_s[pp][d8];
            float4 t1 = *(const float4*)&t_s[pp][d8+4];
            a8[0] = fmaf(qv, t0.x, a8[0]); a8[1] = fmaf(qv, t0.y, a8[1]);
            a8[2] = fmaf(qv, t0.z, a8[2]); a8[3] = fmaf(qv, t0.w, a8[3]);
            a8[4] = fmaf(qv, t1.x, a8[4]); a8[5] = fmaf(qv, t1.y, a8[5]);
            a8[6] = fmaf(qv, t1.z, a8[6]); a8[7] = fmaf(qv, t1.w, a8[7]);
        }
        __syncthreads();
    }
    #pragma unroll
    for (int j = 0; j < 8; j++) atomicAdd(&mu_acc[mm*128 + d8 + j], a8[j]);
    if ((tid & 15) == 0) atomicAdd(&ht_acc[b*16 + mm], htl);
}

// ---------------------------------------------------------------- finalize: denom, mu, C_new, kl
__global__ __launch_bounds__(256) void finalize_kernel(
    const float* __restrict__ C, const float* __restrict__ hs_acc,
    const float* __restrict__ ht_acc, const float* __restrict__ mu_acc,
    float* __restrict__ out)
{
    __shared__ float denom_s[16];
    __shared__ float red[256];
    int tid = threadIdx.x;
    if (tid < 16) {
        float s = 0.f;
        #pragma unroll
        for (int bb = 0; bb < 32; bb++) s += ht_acc[bb*16 + tid];
        denom_s[tid] = s + 1e-6f;
    }
    __syncthreads();
    int m = tid >> 4, dbase = (tid & 15) * 8;
    float v[8]; float ss = 0.f;
    #pragma unroll
    for (int j = 0; j < 8; j++) {
        v[j] = mu_acc[m*128 + dbase + j] / denom_s[m];
        ss = fmaf(v[j], v[j], ss);
    }
    ss += __shfl_xor(ss, 1); ss += __shfl_xor(ss, 2);
    ss += __shfl_xor(ss, 4); ss += __shfl_xor(ss, 8);
    float invn = 1.f / fmaxf(sqrtf(ss), 1e-12f);
    float cn[8]; float cs = 0.f;
    #pragma unroll
    for (int j = 0; j < 8; j++) {
        cn[j] = 0.99f * C[m*128 + dbase + j] + 0.01f * (v[j] * invn);
        cs = fmaf(cn[j], cn[j], cs);
    }
    cs += __shfl_xor(cs, 1); cs += __shfl_xor(cs, 2);
    cs += __shfl_xor(cs, 4); cs += __shfl_xor(cs, 8);
    float invc = 1.f / fmaxf(sqrtf(cs), 1e-12f);
    #pragma unroll
    for (int j = 0; j < 8; j++) out[1 + m*128 + dbase + j] = cn[j] * invc;

    float kacc = 0.f;
    for (int idx = tid; idx < 512; idx += 256) {
        float htv = ht_acc[idx] * (1.f/4096.f);
        float hsv = hs_acc[idx] * (1.f/4096.f);
        float t1 = (htv > 0.f) ? htv * logf(htv) : 0.f;
        kacc += t1 - htv * logf(hsv + 1e-12f);
    }
    red[tid] = kacc;
    __syncthreads();
    for (int s2 = 128; s2 > 0; s2 >>= 1) {
        if (tid < s2) red[tid] += red[tid + s2];
        __syncthreads();
    }
    if (tid == 0) out[0] = red[0] * (1.f/32.f);
}

extern "C" void kernel_launch(void* const* d_in, const int* in_sizes, int n_in,
                              void* d_out, int out_size, void* d_ws, size_t ws_size,
                              hipStream_t stream) {
    const float* fs4 = (const float*)d_in[0];
    const float* ft  = (const float*)d_in[1];
    const float* Ws  = (const float*)d_in[2];
    const float* Wt  = (const float*)d_in[3];
    const float* C   = (const float*)d_in[4];
    float* out = (float*)d_out;
    float* ws  = (float*)d_ws;
    float* hs_acc = ws + WS_HS;
    float* ht_acc = ws + WS_HT;
    float* mu_acc = ws + WS_MU;
    float* tl  = ws + WS_TL;
    float* tlC = ws + WS_TLC;
    ushort* Wsh = (ushort*)(ws + WS_WSH);
    ushort* Wsl = (ushort*)(ws + WS_WSL);
    ushort* Wth = (ushort*)(ws + WS_WTH);
    ushort* Wtl = (ushort*)(ws + WS_WTL);

    hipMemsetAsync(ws, 0, 3072 * sizeof(float), stream);
    hipLaunchKernelGGL(prep_kernel, dim3(480), dim3(256), 0, stream,
                       C, Ws, Wt, Wsh, Wsl, Wth, Wtl);
    hipLaunchKernelGGL((gemm_kernel<true, 256, 4096>), dim3(1024), dim3(256), 0, stream,
                       fs4, Wsh, Wsl, hs_acc, nullptr, nullptr);
    hipLaunchKernelGGL((gemm_kernel<false, 512, 1024>), dim3(256), dim3(256), 0, stream,
                       ft, Wth, Wtl, nullptr, tl, tlC);
    hipLaunchKernelGGL(teacher_highres_kernel, dim3(512), dim3(256), 0, stream,
                       tl, tlC, ht_acc, mu_acc);
    hipLaunchKernelGGL(finalize_kernel, dim3(1), dim3(256), 0, stream,
                       C, hs_acc, ht_acc, mu_acc, out);
}

// Round 8
// 419.315 us; speedup vs baseline: 1.4594x; 1.1030x over previous
//
#include <hip/hip_runtime.h>
#include <math.h>

#define TAU_INV 14.285714285714286f

using short8 = __attribute__((ext_vector_type(8))) short;
using f32x4  = __attribute__((ext_vector_type(4))) float;

// ws layout (float offsets)
#define WS_HS   0                          // [512]
#define WS_HT   512                        // [512]
#define WS_MUS  1024                       // [8*2048] mu slices (batch b -> slice b&7)
#define WS_TL   17408                      // [32*1024*128]
#define WS_TLC  (17408 + 32*1024*128)      // [32*1024*16]
#define WS_WSH  (WS_TLC + 32*1024*16)      // ushort[160*256]
#define WS_WSL  (WS_WSH + 20480)
#define WS_WTH  (WS_WSL + 20480)           // ushort[160*512]
#define WS_WTL  (WS_WTH + 40960)

__device__ __forceinline__ uint bf16rne(float f) {
    uint u = __float_as_uint(f);
    return (u + 0x7fffu + ((u >> 16) & 1u)) >> 16;
}

// ---------------------------------------------------------------- prep: pack W(+PC rows) into bf16 hi/lo planes
__global__ __launch_bounds__(256) void prep_kernel(
    const float* __restrict__ C, const float* __restrict__ Ws, const float* __restrict__ Wt,
    ushort* __restrict__ Wsh, ushort* __restrict__ Wsl,
    ushort* __restrict__ Wth, ushort* __restrict__ Wtl)
{
    int id = blockIdx.x * 256 + threadIdx.x;
    float v; ushort* H; ushort* L; int idx;
    if (id < 160*256) {
        int row = id >> 8, c = id & 255;
        if (row < 128) v = Ws[row*256 + c];
        else if (row < 144) {
            v = 0.f; int m = row - 128;
            #pragma unroll 8
            for (int dd = 0; dd < 128; dd++) v = fmaf(C[m*128+dd], Ws[dd*256 + c], v);
        } else v = 0.f;
        H = Wsh; L = Wsl; idx = id;
    } else {
        int id2 = id - 160*256;
        int row = id2 >> 9, c = id2 & 511;
        if (row < 128) v = Wt[row*512 + c];
        else if (row < 144) {
            v = 0.f; int m = row - 128;
            #pragma unroll 8
            for (int dd = 0; dd < 128; dd++) v = fmaf(C[m*128+dd], Wt[dd*512 + c], v);
        } else v = 0.f;
        H = Wth; L = Wtl; idx = id2;
    }
    uint h = bf16rne(v);
    float hf = __uint_as_float(h << 16);
    uint l = bf16rne(v - hf);
    H[idx] = (ushort)h; L[idx] = (ushort)l;
}

// ---------------------------------------------------------------- split-bf16 MFMA GEMM
template<bool STUDENT, int CIN, int HW>
__global__ __launch_bounds__(256, 2) void gemm_kernel(
    const float* __restrict__ X, const ushort* __restrict__ Wh, const ushort* __restrict__ Wl,
    float* __restrict__ hs_acc, float* __restrict__ tl, float* __restrict__ tlC)
{
    __shared__ __align__(16) ushort Ah[144*32];
    __shared__ __align__(16) ushort Al[144*32];
    __shared__ __align__(16) uint   Bpk[128*32];
    __shared__ float nrm2_lds[128];

    const int tid  = threadIdx.x;
    const int lane = tid & 63;
    const int w    = tid >> 6, wd = w >> 1, wn = w & 1;
    const int g    = lane >> 4, m16 = lane & 15;
    const int ST   = (wd == 0) ? 5 : 4;
    const int tiles_b = HW / 128;
    const int b   = blockIdx.x / tiles_b;
    const int n0  = (blockIdx.x % tiles_b) * 128;
    const float* Xb = X + (size_t)b * CIN * HW + n0;

    f32x4 acc[5][4];
    #pragma unroll
    for (int i = 0; i < 5; i++)
        #pragma unroll
        for (int j = 0; j < 4; j++) acc[i][j] = (f32x4){0.f, 0.f, 0.f, 0.f};

    const int cb = (tid & 7) * 4;
    const int nf = tid >> 3;

    for (int k0 = 0; k0 < CIN; k0 += 32) {
        #pragma unroll
        for (int r = 0; r < 3; r++) {
            int id = tid + r * 256;
            if (r < 2 || id < 576) {
                int row = id >> 2, slot = id & 3;
                int dst = row * 32 + ((slot ^ (row & 3)) << 3);
                int src = row * CIN + k0 + slot * 8;
                *(uint4*)&Ah[dst] = *(const uint4*)&Wh[src];
                *(uint4*)&Al[dst] = *(const uint4*)&Wl[src];
            }
        }
        float4 vv[4];
        #pragma unroll
        for (int i = 0; i < 4; i++)
            vv[i] = *(const float4*)&Xb[(size_t)(k0 + cb + i) * HW + nf * 4];
        #pragma unroll
        for (int j = 0; j < 4; j++) {
            uint q[4];
            #pragma unroll
            for (int i = 0; i < 4; i++) {
                float f = (j == 0) ? vv[i].x : (j == 1) ? vv[i].y : (j == 2) ? vv[i].z : vv[i].w;
                uint h = bf16rne(f);
                float hf = __uint_as_float(h << 16);
                uint lo = bf16rne(f - hf);
                q[i] = (h << 16) | lo;
            }
            int row = nf * 4 + j;
            int dst = row * 32 + (((tid & 7) ^ (nf & 7)) << 2);
            *(uint4*)&Bpk[dst] = make_uint4(q[0], q[1], q[2], q[3]);
        }
        __syncthreads();

        short8 ah[5], al[5];
        #pragma unroll
        for (int ti = 0; ti < 5; ti++) {
            if (ti < ST) {
                int row = wd * 80 + ti * 16 + m16;
                int ad = row * 32 + ((g ^ (row & 3)) << 3);
                ah[ti] = *(const short8*)&Ah[ad];
                al[ti] = *(const short8*)&Al[ad];
            }
        }
        #pragma unroll
        for (int nj = 0; nj < 4; nj++) {
            int row = wn * 64 + nj * 16 + m16;
            int key = (row >> 2) & 7;
            const uint4 q0 = *(const uint4*)&Bpk[row * 32 + (((2*g)   ^ key) << 2)];
            const uint4 q1 = *(const uint4*)&Bpk[row * 32 + (((2*g+1) ^ key) << 2)];
            uint4 bhv, blv;
            bhv.x = __builtin_amdgcn_perm(q0.y, q0.x, 0x07060302u);
            bhv.y = __builtin_amdgcn_perm(q0.w, q0.z, 0x07060302u);
            bhv.z = __builtin_amdgcn_perm(q1.y, q1.x, 0x07060302u);
            bhv.w = __builtin_amdgcn_perm(q1.w, q1.z, 0x07060302u);
            blv.x = __builtin_amdgcn_perm(q0.y, q0.x, 0x05040100u);
            blv.y = __builtin_amdgcn_perm(q0.w, q0.z, 0x05040100u);
            blv.z = __builtin_amdgcn_perm(q1.y, q1.x, 0x05040100u);
            blv.w = __builtin_amdgcn_perm(q1.w, q1.z, 0x05040100u);
            short8 bh = *(short8*)&bhv;
            short8 bl = *(short8*)&blv;
            #pragma unroll
            for (int ti = 0; ti < 5; ti++) {
                if (ti < ST) {
                    acc[ti][nj] = __builtin_amdgcn_mfma_f32_16x16x32_bf16(ah[ti], bh, acc[ti][nj], 0, 0, 0);
                    acc[ti][nj] = __builtin_amdgcn_mfma_f32_16x16x32_bf16(al[ti], bh, acc[ti][nj], 0, 0, 0);
                    acc[ti][nj] = __builtin_amdgcn_mfma_f32_16x16x32_bf16(ah[ti], bl, acc[ti][nj], 0, 0, 0);
                }
            }
        }
        __syncthreads();
    }

    if constexpr (STUDENT) {
        float nrm_own[4];
        #pragma unroll
        for (int nj = 0; nj < 4; nj++) {
            float v = 0.f;
            int st = (wd == 0) ? 5 : 3;
            #pragma unroll
            for (int ti = 0; ti < 5; ti++) {
                if (ti < st) {
                    f32x4 a = acc[ti][nj];
                    v = fmaf(a.x, a.x, v); v = fmaf(a.y, a.y, v);
                    v = fmaf(a.z, a.z, v); v = fmaf(a.w, a.w, v);
                }
            }
            v += __shfl_xor(v, 16); v += __shfl_xor(v, 32);
            nrm_own[nj] = v;
        }
        if (wd == 0 && g == 0) {
            #pragma unroll
            for (int nj = 0; nj < 4; nj++)
                nrm2_lds[wn * 64 + nj * 16 + m16] = nrm_own[nj];
        }
        __syncthreads();
        if (wd == 1) {
            float hsl[4] = {0.f, 0.f, 0.f, 0.f};
            #pragma unroll
            for (int nj = 0; nj < 4; nj++) {
                int nloc = wn * 64 + nj * 16 + m16;
                float nrm2 = nrm2_lds[nloc] + nrm_own[nj];
                float sc = TAU_INV / fmaxf(sqrtf(nrm2), 1e-12f);
                float e0 = acc[3][nj].x * sc, e1 = acc[3][nj].y * sc;
                float e2 = acc[3][nj].z * sc, e3 = acc[3][nj].w * sc;
                float mx = fmaxf(fmaxf(e0, e1), fmaxf(e2, e3));
                mx = fmaxf(mx, __shfl_xor(mx, 16)); mx = fmaxf(mx, __shfl_xor(mx, 32));
                e0 = expf(e0 - mx); e1 = expf(e1 - mx); e2 = expf(e2 - mx); e3 = expf(e3 - mx);
                float s = e0 + e1 + e2 + e3;
                s += __shfl_xor(s, 16); s += __shfl_xor(s, 32);
                float is = 1.f / s;
                hsl[0] = fmaf(e0, is, hsl[0]); hsl[1] = fmaf(e1, is, hsl[1]);
                hsl[2] = fmaf(e2, is, hsl[2]); hsl[3] = fmaf(e3, is, hsl[3]);
            }
            #pragma unroll
            for (int r = 0; r < 4; r++) {
                float v = hsl[r];
                v += __shfl_xor(v, 1); v += __shfl_xor(v, 2);
                v += __shfl_xor(v, 4); v += __shfl_xor(v, 8);
                if (m16 == 0) atomicAdd(&hs_acc[b * 16 + 4 * g + r], v);
            }
        }
    } else {
        #pragma unroll
        for (int ti = 0; ti < 5; ti++) {
            if (ti < ST) {
                int d0 = wd * 80 + ti * 16;
                #pragma unroll
                for (int nj = 0; nj < 4; nj++) {
                    int n = n0 + wn * 64 + nj * 16 + m16;
                    if (d0 < 128)
                        *(f32x4*)&tl[((size_t)(b * 1024 + n)) * 128 + d0 + 4 * g] = acc[ti][nj];
                    else
                        *(f32x4*)&tlC[((size_t)(b * 1024 + n)) * 16 + 4 * g] = acc[ti][nj];
                }
            }
        }
    }
}

// ---------------------------------------------------------------- teacher high-res: barrier-free register pipeline
// grid 1024 = 32 b * 32 block-groups; block 256 = 4 waves; each wave: 32 pixels of one hi-res row.
// lane l owns dims 2l,2l+1; logits replicated across four 16-lane groups (no divergence).
__global__ __launch_bounds__(256) void teacher_highres_kernel(
    const float* __restrict__ tl, const float* __restrict__ tlC,
    float* __restrict__ ht_acc, float* __restrict__ mus)
{
    __shared__ float muL[2048];
    int tid = threadIdx.x;
    int b  = blockIdx.x >> 5;
    int bg = blockIdx.x & 31;
    int w  = tid >> 6, lane = tid & 63;
    int W  = bg * 4 + w;               // 0..127 within batch
    int y  = W >> 1;
    int x0 = (W & 1) * 32;

    #pragma unroll
    for (int i = 0; i < 8; i++) muL[tid + i*256] = 0.f;
    __syncthreads();

    int jy = y >> 1; int r0, r1; float wy0, wy1;
    if ((y & 1) == 0) { r0 = max(jy-1, 0); r1 = jy;            wy0 = 0.25f; wy1 = 0.75f; }
    else              { r0 = jy;           r1 = min(jy+1, 31); wy0 = 0.75f; wy1 = 0.25f; }

    size_t rb0 = (size_t)b*1024 + r0*32;
    size_t rb1 = (size_t)b*1024 + r1*32;
    int d0 = lane * 2;
    int ml = lane & 15;

    float acc[16][2];
    #pragma unroll
    for (int m = 0; m < 16; m++) { acc[m][0] = 0.f; acc[m][1] = 0.f; }
    float htl = 0.f;

    // column cache: colv = y-interp of tl (2 dims), colL = y-interp of tlC[ml]
    float cva0, cva1, cla, cvb0, cvb1, clb;
    {
        int c = max((x0 >> 1) - 1, 0);
        float2 u0 = *(const float2*)&tl[(rb0 + c)*128 + d0];
        float2 u1 = *(const float2*)&tl[(rb1 + c)*128 + d0];
        cva0 = wy0*u0.x + wy1*u1.x; cva1 = wy0*u0.y + wy1*u1.y;
        cla  = wy0*tlC[(rb0 + c)*16 + ml] + wy1*tlC[(rb1 + c)*16 + ml];
    }
    {
        int c = x0 >> 1;
        float2 u0 = *(const float2*)&tl[(rb0 + c)*128 + d0];
        float2 u1 = *(const float2*)&tl[(rb1 + c)*128 + d0];
        cvb0 = wy0*u0.x + wy1*u1.x; cvb1 = wy0*u0.y + wy1*u1.y;
        clb  = wy0*tlC[(rb0 + c)*16 + ml] + wy1*tlC[(rb1 + c)*16 + ml];
    }

    for (int xi = 0; xi < 32; xi++) {
        int x = x0 + xi;
        float t0, t1, lg;
        if ((x & 1) == 0) {
            t0 = 0.25f*cva0 + 0.75f*cvb0;
            t1 = 0.25f*cva1 + 0.75f*cvb1;
            lg = 0.25f*cla  + 0.75f*clb;
        } else {
            int c = min((x >> 1) + 1, 31);
            float2 u0 = *(const float2*)&tl[(rb0 + c)*128 + d0];
            float2 u1 = *(const float2*)&tl[(rb1 + c)*128 + d0];
            float cvc0 = wy0*u0.x + wy1*u1.x;
            float cvc1 = wy0*u0.y + wy1*u1.y;
            float clc  = wy0*tlC[(rb0 + c)*16 + ml] + wy1*tlC[(rb1 + c)*16 + ml];
            t0 = 0.75f*cvb0 + 0.25f*cvc0;
            t1 = 0.75f*cvb1 + 0.25f*cvc1;
            lg = 0.75f*clb  + 0.25f*clc;
            cva0 = cvb0; cva1 = cvb1; cla = clb;
            cvb0 = cvc0; cvb1 = cvc1; clb = clc;
        }
        float nr = t0*t0 + t1*t1;
        nr += __shfl_xor(nr, 1);  nr += __shfl_xor(nr, 2);  nr += __shfl_xor(nr, 4);
        nr += __shfl_xor(nr, 8);  nr += __shfl_xor(nr, 16); nr += __shfl_xor(nr, 32);
        float inv = 1.f / fmaxf(sqrtf(nr), 1e-12f);
        float e = lg * inv * TAU_INV;
        float mx = e;
        mx = fmaxf(mx, __shfl_xor(mx, 1)); mx = fmaxf(mx, __shfl_xor(mx, 2));
        mx = fmaxf(mx, __shfl_xor(mx, 4)); mx = fmaxf(mx, __shfl_xor(mx, 8));
        float ee = expf(e - mx);
        float s = ee;
        s += __shfl_xor(s, 1); s += __shfl_xor(s, 2); s += __shfl_xor(s, 4); s += __shfl_xor(s, 8);
        float qt = ee / s;
        htl += qt;
        float qs = qt * inv;
        #pragma unroll
        for (int m = 0; m < 16; m++) {
            float qv = __shfl(qs, m);
            acc[m][0] = fmaf(qv, t0, acc[m][0]);
            acc[m][1] = fmaf(qv, t1, acc[m][1]);
        }
    }
    #pragma unroll
    for (int m = 0; m < 16; m++) {
        atomicAdd(&muL[m*128 + d0],     acc[m][0]);
        atomicAdd(&muL[m*128 + d0 + 1], acc[m][1]);
    }
    if (lane < 16) atomicAdd(&ht_acc[b*16 + ml], htl);
    __syncthreads();
    float* slice = mus + (b & 7) * 2048;
    #pragma unroll
    for (int i = 0; i < 8; i++) {
        int idx = tid + i*256;
        atomicAdd(&slice[idx], muL[idx]);
    }
}

// ---------------------------------------------------------------- finalize: denom, mu (8 slices), C_new, kl
__global__ __launch_bounds__(256) void finalize_kernel(
    const float* __restrict__ C, const float* __restrict__ hs_acc,
    const float* __restrict__ ht_acc, const float* __restrict__ mus,
    float* __restrict__ out)
{
    __shared__ float denom_s[16];
    __shared__ float red[256];
    int tid = threadIdx.x;
    if (tid < 16) {
        float s = 0.f;
        #pragma unroll
        for (int bb = 0; bb < 32; bb++) s += ht_acc[bb*16 + tid];
        denom_s[tid] = s + 1e-6f;
    }
    __syncthreads();
    int m = tid >> 4, dbase = (tid & 15) * 8;
    float v[8] = {0.f,0.f,0.f,0.f,0.f,0.f,0.f,0.f};
    #pragma unroll
    for (int sl = 0; sl < 8; sl++) {
        const float* p = mus + sl*2048 + m*128 + dbase;
        float4 a = *(const float4*)p;
        float4 bq = *(const float4*)(p + 4);
        v[0] += a.x;  v[1] += a.y;  v[2] += a.z;  v[3] += a.w;
        v[4] += bq.x; v[5] += bq.y; v[6] += bq.z; v[7] += bq.w;
    }
    float ss = 0.f;
    #pragma unroll
    for (int j = 0; j < 8; j++) {
        v[j] = v[j] / denom_s[m];
        ss = fmaf(v[j], v[j], ss);
    }
    ss += __shfl_xor(ss, 1); ss += __shfl_xor(ss, 2);
    ss += __shfl_xor(ss, 4); ss += __shfl_xor(ss, 8);
    float invn = 1.f / fmaxf(sqrtf(ss), 1e-12f);
    float cn[8]; float cs = 0.f;
    #pragma unroll
    for (int j = 0; j < 8; j++) {
        cn[j] = 0.99f * C[m*128 + dbase + j] + 0.01f * (v[j] * invn);
        cs = fmaf(cn[j], cn[j], cs);
    }
    cs += __shfl_xor(cs, 1); cs += __shfl_xor(cs, 2);
    cs += __shfl_xor(cs, 4); cs += __shfl_xor(cs, 8);
    float invc = 1.f / fmaxf(sqrtf(cs), 1e-12f);
    #pragma unroll
    for (int j = 0; j < 8; j++) out[1 + m*128 + dbase + j] = cn[j] * invc;

    float kacc = 0.f;
    for (int idx = tid; idx < 512; idx += 256) {
        float htv = ht_acc[idx] * (1.f/4096.f);
        float hsv = hs_acc[idx] * (1.f/4096.f);
        float t1 = (htv > 0.f) ? htv * logf(htv) : 0.f;
        kacc += t1 - htv * logf(hsv + 1e-12f);
    }
    red[tid] = kacc;
    __syncthreads();
    for (int s2 = 128; s2 > 0; s2 >>= 1) {
        if (tid < s2) red[tid] += red[tid + s2];
        __syncthreads();
    }
    if (tid == 0) out[0] = red[0] * (1.f/32.f);
}

extern "C" void kernel_launch(void* const* d_in, const int* in_sizes, int n_in,
                              void* d_out, int out_size, void* d_ws, size_t ws_size,
                              hipStream_t stream) {
    const float* fs4 = (const float*)d_in[0];
    const float* ft  = (const float*)d_in[1];
    const float* Ws  = (const float*)d_in[2];
    const float* Wt  = (const float*)d_in[3];
    const float* C   = (const float*)d_in[4];
    float* out = (float*)d_out;
    float* ws  = (float*)d_ws;
    float* hs_acc = ws + WS_HS;
    float* ht_acc = ws + WS_HT;
    float* mus = ws + WS_MUS;
    float* tl  = ws + WS_TL;
    float* tlC = ws + WS_TLC;
    ushort* Wsh = (ushort*)(ws + WS_WSH);
    ushort* Wsl = (ushort*)(ws + WS_WSL);
    ushort* Wth = (ushort*)(ws + WS_WTH);
    ushort* Wtl = (ushort*)(ws + WS_WTL);

    hipMemsetAsync(ws, 0, 17408 * sizeof(float), stream);
    hipLaunchKernelGGL(prep_kernel, dim3(480), dim3(256), 0, stream,
                       C, Ws, Wt, Wsh, Wsl, Wth, Wtl);
    hipLaunchKernelGGL((gemm_kernel<true, 256, 4096>), dim3(1024), dim3(256), 0, stream,
                       fs4, Wsh, Wsl, hs_acc, nullptr, nullptr);
    hipLaunchKernelGGL((gemm_kernel<false, 512, 1024>), dim3(256), dim3(256), 0, stream,
                       ft, Wth, Wtl, nullptr, tl, tlC);
    hipLaunchKernelGGL(teacher_highres_kernel, dim3(1024), dim3(256), 0, stream,
                       tl, tlC, ht_acc, mus);
    hipLaunchKernelGGL(finalize_kernel, dim3(1), dim3(256), 0, stream,
                       C, hs_acc, ht_acc, mus, out);
}